// Round 8
// baseline (1003.731 us; speedup 1.0000x reference)
//
#include <hip/hip_runtime.h>
#include <math.h>

#define BATCH 8
#define KQ 256
#define DIM 50257
#define KNN 8
#define N_CLASS 4
#define INV_T 20.0f       // 1/0.05
#define LL2STRIDE 50260   // DIM+2 rounded up to multiple of 4
#define NBK (BATCH * KQ)  // 2048 real blocks
#define REPS 4            // instrumentation: 4x identical work per mega-dispatch

typedef float vf4 __attribute__((ext_vector_type(4)));

__device__ __forceinline__ vf4 nt_load4(const float* p) {
    return __builtin_nontemporal_load((const vf4*)p);
}

// ---------------- kernel 1: 2 shift-copies of log(logits) ----------------
__global__ __launch_bounds__(256) void log_logits_kernel(
        const float* __restrict__ logits, float* __restrict__ ll2, int n) {
    int i = blockIdx.x * 256 + threadIdx.x;     // i = b*DIM + d
    if (i >= n) return;
    int b = i / DIM;
    int d = i - b * DIM;
    float v = __logf(logits[i]);
    #pragma unroll
    for (int s = 0; s < 2; ++s)
        ll2[((size_t)(s * BATCH + b)) * LL2STRIDE + s + d] = v;
}

// ---------------- kernel 2a: FULL dists (qa + table), 4 reps ----------------
// blockIdx = rep*2048 + bk. rep 0 writes the real dists; reps 1-3 write scratch.
// Body identical to R7's verified kernel.
__global__ __launch_bounds__(256) void dists_full_kernel(
        const float* __restrict__ qa, const float* __restrict__ ll2,
        float* __restrict__ outbuf) {
    const int rep = blockIdx.x >> 11;
    const int bk  = blockIdx.x & (NBK - 1);     // b*256 + k
    const int b   = bk >> 8;
    const int c   = bk & 3;
    const int s   = bk & 1;
    const float* __restrict__ qrow  = qa  + (size_t)bk * DIM;
    const float* __restrict__ lrow2 = ll2 + ((size_t)(s * BATCH + b)) * LL2STRIDE + s;

    const int peel = (4 - c) & 3;
    const int nv   = (DIM - peel) >> 2;
    const int tail = peel + nv * 4;
    const int t = threadIdx.x;

    float ax = 0.f, ay = 0.f, az = 0.f, aw = 0.f;
    const float*  __restrict__ qbase = qrow + peel;
    const float2* __restrict__ l2 = (const float2*)(lrow2 + peel);

    int i = t;
    for (; i + 768 < nv; i += 1024) {
        vf4 q0 = nt_load4(qbase + 4 * i);
        vf4 q1 = nt_load4(qbase + 4 * (i + 256));
        vf4 q2 = nt_load4(qbase + 4 * (i + 512));
        vf4 q3 = nt_load4(qbase + 4 * (i + 768));
        float2 l0a = l2[2 * i],             l0b = l2[2 * i + 1];
        float2 l1a = l2[2 * (i + 256)],     l1b = l2[2 * (i + 256) + 1];
        float2 l2a = l2[2 * (i + 512)],     l2b = l2[2 * (i + 512) + 1];
        float2 l3a = l2[2 * (i + 768)],     l3b = l2[2 * (i + 768) + 1];
        ax += q0.x * (__logf(q0.x) - l0a.x);
        ay += q0.y * (__logf(q0.y) - l0a.y);
        az += q0.z * (__logf(q0.z) - l0b.x);
        aw += q0.w * (__logf(q0.w) - l0b.y);
        ax += q1.x * (__logf(q1.x) - l1a.x);
        ay += q1.y * (__logf(q1.y) - l1a.y);
        az += q1.z * (__logf(q1.z) - l1b.x);
        aw += q1.w * (__logf(q1.w) - l1b.y);
        ax += q2.x * (__logf(q2.x) - l2a.x);
        ay += q2.y * (__logf(q2.y) - l2a.y);
        az += q2.z * (__logf(q2.z) - l2b.x);
        aw += q2.w * (__logf(q2.w) - l2b.y);
        ax += q3.x * (__logf(q3.x) - l3a.x);
        ay += q3.y * (__logf(q3.y) - l3a.y);
        az += q3.z * (__logf(q3.z) - l3b.x);
        aw += q3.w * (__logf(q3.w) - l3b.y);
    }
    for (; i < nv; i += 256) {
        vf4 q = nt_load4(qbase + 4 * i);
        float2 la = l2[2 * i], lb = l2[2 * i + 1];
        ax += q.x * (__logf(q.x) - la.x);
        ay += q.y * (__logf(q.y) - la.y);
        az += q.z * (__logf(q.z) - lb.x);
        aw += q.w * (__logf(q.w) - lb.y);
    }
    float sacc = (ax + ay) + (az + aw);

    if (t < peel) {
        float q = qrow[t];
        sacc += q * (__logf(q) - lrow2[t]);
    }
    int tn = DIM - tail;
    if (t >= 4 && t < 4 + tn) {
        int d = tail + (t - 4);
        float q = qrow[d];
        sacc += q * (__logf(q) - lrow2[d]);
    }

    for (int o = 32; o > 0; o >>= 1) sacc += __shfl_xor(sacc, o, 64);
    __shared__ float part[4];
    if ((t & 63) == 0) part[t >> 6] = sacc;
    __syncthreads();
    if (t == 0) {
        float tot = (part[0] + part[1]) + (part[2] + part[3]);
        outbuf[rep * NBK + bk] = tot * (1.0f / (float)DIM);
    }
}

// ---------------- kernel 2b: qa-only ablation (no table loads), 4 reps ------
// Measures the pure qa-stream + log speed: sum qa*log(qa). All reps -> scratch.
__global__ __launch_bounds__(256) void dists_qaonly_kernel(
        const float* __restrict__ qa, float* __restrict__ outbuf) {
    const int rep = blockIdx.x >> 11;
    const int bk  = blockIdx.x & (NBK - 1);
    const int c   = bk & 3;
    const float* __restrict__ qrow = qa + (size_t)bk * DIM;

    const int peel = (4 - c) & 3;
    const int nv   = (DIM - peel) >> 2;
    const int tail = peel + nv * 4;
    const int t = threadIdx.x;

    float ax = 0.f, ay = 0.f, az = 0.f, aw = 0.f;
    const float* __restrict__ qbase = qrow + peel;

    int i = t;
    for (; i + 768 < nv; i += 1024) {
        vf4 q0 = nt_load4(qbase + 4 * i);
        vf4 q1 = nt_load4(qbase + 4 * (i + 256));
        vf4 q2 = nt_load4(qbase + 4 * (i + 512));
        vf4 q3 = nt_load4(qbase + 4 * (i + 768));
        ax += q0.x * __logf(q0.x);
        ay += q0.y * __logf(q0.y);
        az += q0.z * __logf(q0.z);
        aw += q0.w * __logf(q0.w);
        ax += q1.x * __logf(q1.x);
        ay += q1.y * __logf(q1.y);
        az += q1.z * __logf(q1.z);
        aw += q1.w * __logf(q1.w);
        ax += q2.x * __logf(q2.x);
        ay += q2.y * __logf(q2.y);
        az += q2.z * __logf(q2.z);
        aw += q2.w * __logf(q2.w);
        ax += q3.x * __logf(q3.x);
        ay += q3.y * __logf(q3.y);
        az += q3.z * __logf(q3.z);
        aw += q3.w * __logf(q3.w);
    }
    for (; i < nv; i += 256) {
        vf4 q = nt_load4(qbase + 4 * i);
        ax += q.x * __logf(q.x);
        ay += q.y * __logf(q.y);
        az += q.z * __logf(q.z);
        aw += q.w * __logf(q.w);
    }
    float sacc = (ax + ay) + (az + aw);
    if (t < peel) { float q = qrow[t]; sacc += q * __logf(q); }
    int tn = DIM - tail;
    if (t >= 4 && t < 4 + tn) { int d = tail + (t - 4); float q = qrow[d]; sacc += q * __logf(q); }

    for (int o = 32; o > 0; o >>= 1) sacc += __shfl_xor(sacc, o, 64);
    __shared__ float part[4];
    if ((t & 63) == 0) part[t >> 6] = sacc;
    __syncthreads();
    if (t == 0) {
        float tot = (part[0] + part[1]) + (part[2] + part[3]);
        outbuf[rep * NBK + bk] = tot * (1.0f / (float)DIM);
    }
}

// ---------------- kernel 3: top-8 + softmax + class scatter ----------------
__global__ __launch_bounds__(64) void topk_kernel(
        const float* __restrict__ dists, const int* __restrict__ labels,
        float* __restrict__ out) {
    const int b = blockIdx.x;
    const int lane = threadIdx.x;
    const int base = lane * 4;
    const float* __restrict__ drow = dists + b * KQ;

    float v[4];
    #pragma unroll
    for (int j = 0; j < 4; ++j) v[j] = -INV_T * drow[base + j];

    float topv[KNN]; int topi[KNN];
    #pragma unroll
    for (int it = 0; it < KNN; ++it) {
        float lv = v[0]; int li = base;
        #pragma unroll
        for (int j = 1; j < 4; ++j)
            if (v[j] > lv || (v[j] == lv && base + j < li)) { lv = v[j]; li = base + j; }
        #pragma unroll
        for (int o = 32; o > 0; o >>= 1) {
            float ov = __shfl_xor(lv, o, 64);
            int   oi = __shfl_xor(li, o, 64);
            if (ov > lv || (ov == lv && oi < li)) { lv = ov; li = oi; }
        }
        topv[it] = lv; topi[it] = li;
        if (li >= base && li < base + 4) v[li - base] = -INFINITY;
    }

    if (lane == 0) {
        float m = topv[0];
        float w[KNN], sum = 0.f;
        #pragma unroll
        for (int i = 0; i < KNN; ++i) { w[i] = __expf(topv[i] - m); sum += w[i]; }
        float p[N_CLASS] = {0.f, 0.f, 0.f, 0.f};
        #pragma unroll
        for (int i = 0; i < KNN; ++i) p[labels[b * KQ + topi[i]]] += w[i];
        float inv = 1.0f / sum;
        #pragma unroll
        for (int c = 0; c < N_CLASS; ++c) out[b * N_CLASS + c] = p[c] * inv;
    }
}

extern "C" void kernel_launch(void* const* d_in, const int* in_sizes, int n_in,
                              void* d_out, int out_size, void* d_ws, size_t ws_size,
                              hipStream_t stream) {
    const float* logits = (const float*)d_in[0];   // [B, DIM]
    const float* qa     = (const float*)d_in[1];   // [B, K, DIM]
    const int*   labels = (const int*)d_in[2];     // [B, K]
    float* out = (float*)d_out;                    // [B, N_CLASS]

    // ws layout: ll2 table, then dists_full[REPS*NBK], then dists_qaonly[REPS*NBK]
    float* ll2     = (float*)d_ws;
    float* dfull   = ll2 + (size_t)2 * BATCH * LL2STRIDE;
    float* dqaonly = dfull + (size_t)REPS * NBK;

    const int n_ll = BATCH * DIM;
    log_logits_kernel<<<(n_ll + 255) / 256, 256, 0, stream>>>(logits, ll2, n_ll);
    dists_full_kernel<<<REPS * NBK, 256, 0, stream>>>(qa, ll2, dfull);      // rep0 = real
    dists_qaonly_kernel<<<REPS * NBK, 256, 0, stream>>>(qa, dqaonly);       // ablation
    topk_kernel<<<BATCH, 64, 0, stream>>>(dfull, labels, out);
}